// Round 5
// baseline (279.553 us; speedup 1.0000x reference)
//
#include <hip/hip_runtime.h>
#include <math.h>

#define S 8192
#define E 64
#define CAP 256
static const long long NOUT = (long long)S * E * CAP;  // 134,217,728 elems per output
static const long long NQ   = (2 * NOUT) / 4;          // 67,108,864 float4s total

typedef float f32x4 __attribute__((ext_vector_type(4)));

// ---------------------------------------------------------------------------
// Kernel A: per-row fp32 softmax + top-1/top-2 selection.
// One wave (64 lanes) per row; lane == expert index. 4 rows per block.
// ---------------------------------------------------------------------------
__global__ void softmax_top2(const float* __restrict__ in,
                             int* __restrict__ idx1, int* __restrict__ idx2,
                             float* __restrict__ w1, float* __restrict__ w2) {
    const int lane = threadIdx.x;          // 0..63, == expert id
    const int row  = blockIdx.x * 4 + threadIdx.y;

    float x = in[row * E + lane];

    float mx = x;
    #pragma unroll
    for (int o = 32; o > 0; o >>= 1) mx = fmaxf(mx, __shfl_xor(mx, o));

    float p = __expf(x - mx);
    float sum = p;
    #pragma unroll
    for (int o = 32; o > 0; o >>= 1) sum += __shfl_xor(sum, o);
    float prob = p / sum;

    // argmax on x (monotonic w.r.t. softmax), first-index tie-break
    float v = x; int idx = lane;
    #pragma unroll
    for (int o = 32; o > 0; o >>= 1) {
        float ov = __shfl_xor(v, o);
        int   oi = __shfl_xor(idx, o);
        if (ov > v || (ov == v && oi < idx)) { v = ov; idx = oi; }
    }
    const int i1 = idx;

    float x2 = (lane == i1) ? -INFINITY : x;
    v = x2; idx = lane;
    #pragma unroll
    for (int o = 32; o > 0; o >>= 1) {
        float ov = __shfl_xor(v, o);
        int   oi = __shfl_xor(idx, o);
        if (ov > v || (ov == v && oi < idx)) { v = ov; idx = oi; }
    }
    const int i2 = idx;

    const float pw1 = __shfl(prob, i1);
    const float pw2 = __shfl(prob, i2);

    if (lane == 0) {
        idx1[row] = i1;
        idx2[row] = i2;
        w1[row]   = pw1;
        w2[row]   = pw2;
    }
}

// ---------------------------------------------------------------------------
// Kernel B: exclusive rank per expert, 4 waves per expert-block.
// Wave w owns tokens [w*2048, (w+1)*2048). Phase 1: per-wave match counts.
// Phase 2 (after LDS exchange): per-wave exclusive base, then ballot-prefix
// ranks. rank2 base offset by total top-1 count for this expert.
// ---------------------------------------------------------------------------
__global__ __launch_bounds__(256) void rank_kernel(
        const int* __restrict__ idx1, const int* __restrict__ idx2,
        int* __restrict__ rank1, int* __restrict__ rank2) {
    const int e    = blockIdx.x;
    const int lane = threadIdx.x & 63;
    const int w    = threadIdx.x >> 6;        // wave 0..3
    const int seg  = S / 4;                   // 2048 tokens per wave
    const int t0w  = w * seg;
    const unsigned long long below = (1ULL << lane) - 1ULL;

    __shared__ int c1s[4], c2s[4];

    int c1 = 0, c2 = 0;
    #pragma unroll 4
    for (int t0 = t0w; t0 < t0w + seg; t0 += 64) {
        const int t = t0 + lane;
        c1 += __popcll(__ballot(idx1[t] == e));
        c2 += __popcll(__ballot(idx2[t] == e));
    }
    if (lane == 0) { c1s[w] = c1; c2s[w] = c2; }
    __syncthreads();

    const int tot1 = c1s[0] + c1s[1] + c1s[2] + c1s[3];
    int off1 = 0, off2 = tot1;
    for (int k = 0; k < w; ++k) { off1 += c1s[k]; off2 += c2s[k]; }

    int base = off1;
    #pragma unroll 4
    for (int t0 = t0w; t0 < t0w + seg; t0 += 64) {
        const int t = t0 + lane;
        const int iv = idx1[t];
        const unsigned long long m = __ballot(iv == e);
        if (iv == e) rank1[t] = base + __popcll(m & below);
        base += __popcll(m);
    }
    base = off2;
    #pragma unroll 4
    for (int t0 = t0w; t0 < t0w + seg; t0 += 64) {
        const int t = t0 + lane;
        const int iv = idx2[t];
        const unsigned long long m = __ballot(iv == e);
        if (iv == e) rank2[t] = base + __popcll(m & below);
        base += __popcll(m);
    }
}

// ---------------------------------------------------------------------------
// Kernel C: pure flat zero-fill, rocclr-fill-shaped: grid-stride dwordx4,
// consecutive threads adjacent, independent stores (unroll 4).
// ---------------------------------------------------------------------------
__global__ __launch_bounds__(256) void fill_zero(f32x4* __restrict__ out) {
    const long long stride = (long long)gridDim.x * blockDim.x;   // 524288
    long long i = (long long)blockIdx.x * blockDim.x + threadIdx.x;
    const f32x4 z = {0.f, 0.f, 0.f, 0.f};
    #pragma unroll 4
    for (; i < NQ; i += stride) out[i] = z;
}

// ---------------------------------------------------------------------------
// Kernel D: sparse patch of <=2 entries per token into the zeroed output.
// ---------------------------------------------------------------------------
__global__ void scatter_kernel(const int* __restrict__ idx1,
                               const int* __restrict__ idx2,
                               const float* __restrict__ w1,
                               const float* __restrict__ w2,
                               const int* __restrict__ rank1,
                               const int* __restrict__ rank2,
                               float* __restrict__ out) {
    const int t = blockIdx.x * blockDim.x + threadIdx.x;
    if (t >= S) return;

    float* __restrict__ cb   = out;
    float* __restrict__ mask = out + NOUT;

    const int r1 = rank1[t];
    if (r1 < CAP) {
        const long long off = (long long)t * (E * CAP) + (long long)idx1[t] * CAP + r1;
        const float w = w1[t];
        cb[off]   = w;
        mask[off] = (w != 0.0f) ? 1.0f : 0.0f;
    }
    const int r2 = rank2[t];
    if (r2 < CAP) {
        const long long off = (long long)t * (E * CAP) + (long long)idx2[t] * CAP + r2;
        const float w = w2[t];
        cb[off]   = w;
        mask[off] = (w != 0.0f) ? 1.0f : 0.0f;
    }
}

extern "C" void kernel_launch(void* const* d_in, const int* in_sizes, int n_in,
                              void* d_out, int out_size, void* d_ws, size_t ws_size,
                              hipStream_t stream) {
    const float* in = (const float*)d_in[0];
    float* out = (float*)d_out;

    // workspace layout (8192 each): idx1, idx2, rank1, rank2, w1, w2
    int*   idx1  = (int*)d_ws;
    int*   idx2  = idx1 + S;
    int*   rank1 = idx2 + S;
    int*   rank2 = rank1 + S;
    float* w1    = (float*)(rank2 + S);
    float* w2    = w1 + S;

    fill_zero<<<2048, 256, 0, stream>>>((f32x4*)out);
    softmax_top2<<<S / 4, dim3(64, 4), 0, stream>>>(in, idx1, idx2, w1, w2);
    rank_kernel<<<E, 256, 0, stream>>>(idx1, idx2, rank1, rank2);
    scatter_kernel<<<(S + 255) / 256, 256, 0, stream>>>(idx1, idx2, w1, w2,
                                                        rank1, rank2, out);
}

// Round 6
// 201.576 us; speedup vs baseline: 1.3868x; 1.3868x over previous
//
#include <hip/hip_runtime.h>
#include <math.h>

#define S 8192
#define E 64
#define CAP 256
static const long long NOUT = (long long)S * E * CAP;  // 134,217,728 elems per output
static const long long NQ   = (2 * NOUT) / 4;          // 67,108,864 float4s total

typedef float f32x4 __attribute__((ext_vector_type(4)));

// ---------------------------------------------------------------------------
// Kernel A: per-row fp32 softmax + top-1/top-2 selection.
// One wave (64 lanes) per row; lane == expert index. 4 rows per block.
// ---------------------------------------------------------------------------
__global__ void softmax_top2(const float* __restrict__ in,
                             int* __restrict__ idx1, int* __restrict__ idx2,
                             float* __restrict__ w1, float* __restrict__ w2) {
    const int lane = threadIdx.x;          // 0..63, == expert id
    const int row  = blockIdx.x * 4 + threadIdx.y;

    float x = in[row * E + lane];

    float mx = x;
    #pragma unroll
    for (int o = 32; o > 0; o >>= 1) mx = fmaxf(mx, __shfl_xor(mx, o));

    float p = __expf(x - mx);
    float sum = p;
    #pragma unroll
    for (int o = 32; o > 0; o >>= 1) sum += __shfl_xor(sum, o);
    float prob = p / sum;

    // argmax on x (monotonic w.r.t. softmax), first-index tie-break
    float v = x; int idx = lane;
    #pragma unroll
    for (int o = 32; o > 0; o >>= 1) {
        float ov = __shfl_xor(v, o);
        int   oi = __shfl_xor(idx, o);
        if (ov > v || (ov == v && oi < idx)) { v = ov; idx = oi; }
    }
    const int i1 = idx;

    float x2 = (lane == i1) ? -INFINITY : x;
    v = x2; idx = lane;
    #pragma unroll
    for (int o = 32; o > 0; o >>= 1) {
        float ov = __shfl_xor(v, o);
        int   oi = __shfl_xor(idx, o);
        if (ov > v || (ov == v && oi < idx)) { v = ov; idx = oi; }
    }
    const int i2 = idx;

    const float pw1 = __shfl(prob, i1);
    const float pw2 = __shfl(prob, i2);

    if (lane == 0) {
        idx1[row] = i1;
        idx2[row] = i2;
        w1[row]   = pw1;
        w2[row]   = pw2;
    }
}

// ---------------------------------------------------------------------------
// Kernel B: flat zero-fill, exact rocclr-fillBuffer shape: ONE dwordx4 store
// per thread, 262,144 blocks, no loop.
// ---------------------------------------------------------------------------
__global__ __launch_bounds__(256) void fill_zero(f32x4* __restrict__ out) {
    const size_t i = (size_t)blockIdx.x * 256 + threadIdx.x;
    const f32x4 z = {0.f, 0.f, 0.f, 0.f};
    out[i] = z;
}

// ---------------------------------------------------------------------------
// Kernel C: fused rank + scatter. Block e (4 waves) computes per-expert
// exclusive ranks via ballot-prefix and writes the <=2 output entries per
// matched token directly into the zeroed [S,E,CAP] outputs.
// ---------------------------------------------------------------------------
__global__ __launch_bounds__(256) void rank_scatter(
        const int* __restrict__ idx1, const int* __restrict__ idx2,
        const float* __restrict__ w1, const float* __restrict__ w2,
        float* __restrict__ out) {
    const int e    = blockIdx.x;
    const int lane = threadIdx.x & 63;
    const int w    = threadIdx.x >> 6;        // wave 0..3
    const int seg  = S / 4;                   // 2048 tokens per wave
    const int t0w  = w * seg;
    const unsigned long long below = (1ULL << lane) - 1ULL;

    __shared__ int c1s[4], c2s[4];

    // phase 1: per-wave match counts
    int c1 = 0, c2 = 0;
    #pragma unroll 4
    for (int t0 = t0w; t0 < t0w + seg; t0 += 64) {
        const int t = t0 + lane;
        c1 += __popcll(__ballot(idx1[t] == e));
        c2 += __popcll(__ballot(idx2[t] == e));
    }
    if (lane == 0) { c1s[w] = c1; c2s[w] = c2; }
    __syncthreads();

    const int tot1 = c1s[0] + c1s[1] + c1s[2] + c1s[3];
    int off1 = 0, off2 = tot1;                 // rank2 offset by total top1 count
    for (int k = 0; k < w; ++k) { off1 += c1s[k]; off2 += c2s[k]; }

    // phase 2: ballot-prefix ranks + direct scatter into output
    int base = off1;
    #pragma unroll 4
    for (int t0 = t0w; t0 < t0w + seg; t0 += 64) {
        const int t = t0 + lane;
        const int iv = idx1[t];
        const unsigned long long m = __ballot(iv == e);
        if (iv == e) {
            const int r = base + __popcll(m & below);
            if (r < CAP) {
                const float v = w1[t];
                const long long off = (long long)t * (E * CAP) + e * CAP + r;
                out[off]        = v;
                out[NOUT + off] = (v != 0.0f) ? 1.0f : 0.0f;
            }
        }
        base += __popcll(m);
    }
    base = off2;
    #pragma unroll 4
    for (int t0 = t0w; t0 < t0w + seg; t0 += 64) {
        const int t = t0 + lane;
        const int iv = idx2[t];
        const unsigned long long m = __ballot(iv == e);
        if (iv == e) {
            const int r = base + __popcll(m & below);
            if (r < CAP) {
                const float v = w2[t];
                const long long off = (long long)t * (E * CAP) + e * CAP + r;
                out[off]        = v;
                out[NOUT + off] = (v != 0.0f) ? 1.0f : 0.0f;
            }
        }
        base += __popcll(m);
    }
}

extern "C" void kernel_launch(void* const* d_in, const int* in_sizes, int n_in,
                              void* d_out, int out_size, void* d_ws, size_t ws_size,
                              hipStream_t stream) {
    const float* in = (const float*)d_in[0];
    float* out = (float*)d_out;

    // workspace layout (8192 each): idx1, idx2, w1, w2
    int*   idx1 = (int*)d_ws;
    int*   idx2 = idx1 + S;
    float* w1   = (float*)(idx2 + S);
    float* w2   = w1 + S;

    softmax_top2<<<S / 4, dim3(64, 4), 0, stream>>>(in, idx1, idx2, w1, w2);
    fill_zero<<<(int)(NQ / 256), 256, 0, stream>>>((f32x4*)out);
    rank_scatter<<<E, 256, 0, stream>>>(idx1, idx2, w1, w2, out);
}